// Round 1
// baseline (951.036 us; speedup 1.0000x reference)
//
#include <hip/hip_runtime.h>

#define N_NODES 10000
#define N_CH    32
#define N_EDGES 160000
#define HPAD    16      // padded h row (13 used)
#define SLOTS   8       // nodes per block in k_layer

__device__ __forceinline__ float dot4(float4 a, float4 b) {
    return a.x*b.x + a.y*b.y + a.z*b.z + a.w*b.w;
}

// h[i][ch][m] init: m=0 <- emb_w[atoms[i]][ch], rest 0. Row padded to 16.
__global__ void k_init_h(const int* __restrict__ atoms, const float* __restrict__ emb_w,
                         float* __restrict__ h) {
    int t = blockIdx.x * 256 + threadIdx.x;          // exactly N*C threads
    int i = t >> 5, ch = t & 31;
    float v = emb_w[atoms[i] * N_CH + ch];
    float4* p = (float4*)(h + (size_t)t * HPAD);
    p[0] = make_float4(v, 0.f, 0.f, 0.f);
    p[1] = make_float4(0.f, 0.f, 0.f, 0.f);
    p[2] = make_float4(0.f, 0.f, 0.f, 0.f);
    p[3] = make_float4(0.f, 0.f, 0.f, 0.f);
}

__global__ void k_u(const float* __restrict__ pos, const int* __restrict__ ei,
                    float4* __restrict__ u4) {
    int e = blockIdx.x * 256 + threadIdx.x;          // exactly E threads
    int s = ei[e], d = ei[N_EDGES + e];
    float rx = pos[d*3+0] - pos[s*3+0];
    float ry = pos[d*3+1] - pos[s*3+1];
    float rz = pos[d*3+2] - pos[s*3+2];
    float nrm = sqrtf(rx*rx + ry*ry + rz*rz) + 1e-9f;
    float inv = 1.0f / nrm;
    u4[e] = make_float4(rx*inv, ry*inv, rz*inv, 0.f);
}

__global__ void k_hist(const int* __restrict__ ei, int* __restrict__ deg) {
    int e = blockIdx.x * 256 + threadIdx.x;
    atomicAdd(&deg[ei[N_EDGES + e]], 1);
}

__global__ __launch_bounds__(1024) void k_scan(const int* __restrict__ deg,
                                               int* __restrict__ offs,
                                               int* __restrict__ cursor) {
    __shared__ int part[1024];
    const int t = threadIdx.x;
    const int base = t * 10;
    int s = 0;
#pragma unroll
    for (int r = 0; r < 10; ++r) { int i = base + r; if (i < N_NODES) s += deg[i]; }
    part[t] = s;
    __syncthreads();
    for (int off = 1; off < 1024; off <<= 1) {
        int v = (t >= off) ? part[t - off] : 0;
        __syncthreads();
        part[t] += v;
        __syncthreads();
    }
    int run = (t > 0) ? part[t - 1] : 0;
#pragma unroll
    for (int r = 0; r < 10; ++r) {
        int i = base + r;
        if (i < N_NODES) { offs[i] = run; cursor[i] = run; run += deg[i]; }
    }
    if (t == 0) offs[N_NODES] = N_EDGES;
}

__global__ void k_scatter(const int* __restrict__ ei, int* __restrict__ cursor,
                          int* __restrict__ perm) {
    int e = blockIdx.x * 256 + threadIdx.x;
    int d = ei[N_EDGES + e];
    int p = atomicAdd(&cursor[d], 1);
    perm[p] = e;
}

// One fused layer: per-node edge gather -> T (regs) -> W contraction -> messages
// -> channel/message 32x32 matmuls -> h_out.
__global__ __launch_bounds__(256) void k_layer(
    const int layer,
    const float* __restrict__ hA,        // [N][32][HPAD]
    float* __restrict__ hOut,            // [N][32][outStride]
    const int outStride,
    const int* __restrict__ srcArr,      // edge_index row 0
    const float4* __restrict__ u4,       // [E]
    const int* __restrict__ perm,
    const int* __restrict__ offs,
    const float* __restrict__ W_ab,      // [2][3][3][32][32]
    const float* __restrict__ ws_w,      // [2][3][3][32]
    const float* __restrict__ cw,        // [2][3][N][32][32]
    const float* __restrict__ mw)        // [2][3][N][32][32]
{
    __shared__ __align__(16) float Tlds[SLOTS * 3 * 13 * 32];  // 39936 B (aliased later)
    __shared__ __align__(16) float Wlds[3 * 32 * 36];          // 13824 B (pad 36 vs bank conflicts)

    const int slot = threadIdx.x >> 5;
    const int j    = threadIdx.x & 31;
    const int node = blockIdx.x * SLOTS + slot;   // grid = N/SLOTS exactly

    // ---- edge gather: T[a][m] = sum_{e->node} s_a(e, j) * upow(e, m)
    float T[3][13];
#pragma unroll
    for (int a = 0; a < 3; ++a)
#pragma unroll
        for (int m = 0; m < 13; ++m) T[a][m] = 0.f;

    const int e0 = offs[node], e1 = offs[node + 1];
    for (int idx = e0; idx < e1; ++idx) {
        const int e = perm[idx];
        const float4 u = u4[e];
        const int s = srcArr[e];
        const float* hr = hA + ((size_t)(s * N_CH + j)) * HPAD;
        const float4 a0 = *(const float4*)(hr);
        const float4 a1 = *(const float4*)(hr + 4);
        const float4 a2 = *(const float4*)(hr + 8);
        const float h12 = hr[12];

        float up[13];
        up[0] = 1.f;  up[1] = u.x;      up[2] = u.y;      up[3] = u.z;
        up[4] = u.x*u.x; up[5] = u.x*u.y; up[6] = u.x*u.z;
        up[7] = u.y*u.x; up[8] = u.y*u.y; up[9] = u.y*u.z;
        up[10] = u.z*u.x; up[11] = u.z*u.y; up[12] = u.z*u.z;

        const float s0 = a0.x;
        const float s1 = a0.y*up[1] + a0.z*up[2] + a0.w*up[3];
        float s2 = a1.x*up[4] + a1.y*up[5] + a1.z*up[6] + a1.w*up[7];
        s2 += a2.x*up[8] + a2.y*up[9] + a2.z*up[10] + a2.w*up[11] + h12*up[12];

        const float sa[3] = {s0, s1, s2};
#pragma unroll
        for (int a = 0; a < 3; ++a)
#pragma unroll
            for (int m = 0; m < 13; ++m) T[a][m] += sa[a] * up[m];
    }

    // T -> LDS, layout [slot][a][m][k=j]
#pragma unroll
    for (int a = 0; a < 3; ++a)
#pragma unroll
        for (int m = 0; m < 13; ++m)
            Tlds[((slot * 3 + a) * 13 + m) * 32 + j] = T[a][m];

    // ---- contraction: A_c[node][j][m] = sum_a sum_k W[l,c,a,j,k] * T[a][k][off_c+m]
    float acc[13];
#pragma unroll
    for (int m = 0; m < 13; ++m) acc[m] = 0.f;

#pragma unroll
    for (int c = 0; c < 3; ++c) {
        __syncthreads();  // protects Tlds stores (c==0) and Wlds reuse (c>0)
        const float* wsrc = W_ab + ((size_t)(layer * 3 + c)) * 3 * 1024;
        for (int t = threadIdx.x; t < 3072; t += 256) {
            int a = t >> 10, rem = t & 1023;
            Wlds[a * 1152 + (rem >> 5) * 36 + (rem & 31)] = wsrc[t];
        }
        __syncthreads();
        const int off = (c == 0) ? 0 : ((c == 1) ? 1 : 4);
        const int sz  = (c == 0) ? 1 : ((c == 1) ? 3 : 9);
#pragma unroll
        for (int a = 0; a < 3; ++a) {
            const float* wrow = Wlds + a * 1152 + j * 36;
#pragma unroll
            for (int k4 = 0; k4 < 8; ++k4) {
                const float4 w4 = *(const float4*)(wrow + k4 * 4);
#pragma unroll
                for (int m = 0; m < 9; ++m) {
                    if (m < sz) {
                        const float4 t4 = *(const float4*)&Tlds[((slot * 3 + a) * 13 + off + m) * 32 + k4 * 4];
                        acc[off + m] += dot4(w4, t4);
                    }
                }
            }
        }
    }
    __syncthreads();  // all Tlds reads done; alias region below

    // alias Tlds region: h_old and msg, layout [slot][m][k]
    float* hls = Tlds;                       // SLOTS*13*32 = 3328 floats
    float* mls = Tlds + SLOTS * 13 * 32;     // 3328 floats (6656 <= 9984)

    // messages: msg_c[j][m] = (ws0 + ws1*s0 + ws2*s0^2) * A_c[j][m]  (elementwise in channel)
    const float s0n = acc[0];
    const float s0sq = s0n * s0n;
#pragma unroll
    for (int c = 0; c < 3; ++c) {
        const int off = (c == 0) ? 0 : ((c == 1) ? 1 : 4);
        const int sz  = (c == 0) ? 1 : ((c == 1) ? 3 : 9);
        const float* wsp = ws_w + ((size_t)(layer * 3 + c)) * 3 * 32 + j;
        const float poly = wsp[0] + wsp[32] * s0n + wsp[64] * s0sq;
#pragma unroll
        for (int m = 0; m < 9; ++m)
            if (m < sz) mls[(slot * 13 + off + m) * 32 + j] = poly * acc[off + m];
    }
    {
        const float* hrow = hA + ((size_t)(node * N_CH + j)) * HPAD;
        const float4 a0 = *(const float4*)(hrow);
        const float4 a1 = *(const float4*)(hrow + 4);
        const float4 a2 = *(const float4*)(hrow + 8);
        const float h12 = hrow[12];
        const float hv[13] = {a0.x, a0.y, a0.z, a0.w, a1.x, a1.y, a1.z, a1.w,
                              a2.x, a2.y, a2.z, a2.w, h12};
#pragma unroll
        for (int m = 0; m < 13; ++m) hls[(slot * 13 + m) * 32 + j] = hv[m];
    }
    __syncthreads();

    // ---- update: h_new[j][m] = sum_k cw[l,c,node,j,k]*h_old[k][m] + mw[...]*msg[k][m]
    float out[13];
#pragma unroll
    for (int m = 0; m < 13; ++m) out[m] = 0.f;

#pragma unroll
    for (int c = 0; c < 3; ++c) {
        const int off = (c == 0) ? 0 : ((c == 1) ? 1 : 4);
        const int sz  = (c == 0) ? 1 : ((c == 1) ? 3 : 9);
        const size_t wb = (((size_t)(layer * 3 + c) * N_NODES + node) * 32 + j) * 32;
        const float4* cwr = (const float4*)(cw + wb);
        const float4* mwr = (const float4*)(mw + wb);
        float4 c4[8], m4[8];
#pragma unroll
        for (int k4 = 0; k4 < 8; ++k4) { c4[k4] = cwr[k4]; m4[k4] = mwr[k4]; }
#pragma unroll
        for (int k4 = 0; k4 < 8; ++k4) {
#pragma unroll
            for (int m = 0; m < 9; ++m) {
                if (m < sz) {
                    const float4 h4 = *(const float4*)&hls[(slot * 13 + off + m) * 32 + k4 * 4];
                    const float4 g4 = *(const float4*)&mls[(slot * 13 + off + m) * 32 + k4 * 4];
                    out[off + m] += dot4(c4[k4], h4) + dot4(m4[k4], g4);
                }
            }
        }
    }
    float* orow = hOut + ((size_t)(node * N_CH + j)) * outStride;
#pragma unroll
    for (int m = 0; m < 13; ++m) orow[m] = out[m];
}

extern "C" void kernel_launch(void* const* d_in, const int* in_sizes, int n_in,
                              void* d_out, int out_size, void* d_ws, size_t ws_size,
                              hipStream_t stream) {
    const float* pos   = (const float*)d_in[0];
    const int*   ei    = (const int*)d_in[1];
    const int*   atoms = (const int*)d_in[2];
    const float* emb_w = (const float*)d_in[3];
    const float* W_ab  = (const float*)d_in[4];
    const float* ws_w  = (const float*)d_in[5];
    const float* cw    = (const float*)d_in[6];
    const float* mw    = (const float*)d_in[7];
    float* out = (float*)d_out;

    char* ws = (char*)d_ws;
    float* hA = (float*)ws;   ws += (size_t)N_NODES * N_CH * HPAD * 4;   // 20.48 MB
    float* hB = (float*)ws;   ws += (size_t)N_NODES * N_CH * HPAD * 4;   // 20.48 MB
    float4* u4 = (float4*)ws; ws += (size_t)N_EDGES * 4 * 4;             // 2.56 MB
    int* perm = (int*)ws;     ws += (size_t)N_EDGES * 4;                 // 640 KB
    int* offs = (int*)ws;     ws += (size_t)(N_NODES + 16) * 4;
    int* cursor = (int*)ws;   ws += (size_t)N_NODES * 4;
    int* deg = (int*)ws;      ws += (size_t)N_NODES * 4;

    hipMemsetAsync(deg, 0, N_NODES * 4, stream);
    k_init_h<<<N_NODES * N_CH / 256, 256, 0, stream>>>(atoms, emb_w, hA);
    k_u<<<N_EDGES / 256, 256, 0, stream>>>(pos, ei, u4);
    k_hist<<<N_EDGES / 256, 256, 0, stream>>>(ei, deg);
    k_scan<<<1, 1024, 0, stream>>>(deg, offs, cursor);
    k_scatter<<<N_EDGES / 256, 256, 0, stream>>>(ei, cursor, perm);

    k_layer<<<N_NODES / SLOTS, 256, 0, stream>>>(0, hA, hB, HPAD, ei, u4, perm, offs,
                                                 W_ab, ws_w, cw, mw);
    k_layer<<<N_NODES / SLOTS, 256, 0, stream>>>(1, hB, out, 13, ei, u4, perm, offs,
                                                 W_ab, ws_w, cw, mw);
}

// Round 2
// 724.006 us; speedup vs baseline: 1.3136x; 1.3136x over previous
//
#include <hip/hip_runtime.h>

#define N_NODES 10000
#define N_CH    32
#define N_EDGES 160000
#define HPAD    16      // padded h row (13 used)
#define SLOTS   8       // nodes per block

__device__ __forceinline__ float dot4(float4 a, float4 b) {
    return a.x*b.x + a.y*b.y + a.z*b.z + a.w*b.w;
}

// ---------- CSR build ----------
__global__ void k_hist(const int* __restrict__ ei, int* __restrict__ deg) {
    int e = blockIdx.x * 256 + threadIdx.x;
    atomicAdd(&deg[ei[N_EDGES + e]], 1);
}

__global__ __launch_bounds__(1024) void k_scan(const int* __restrict__ deg,
                                               int* __restrict__ offs,
                                               int* __restrict__ cursor) {
    __shared__ int part[1024];
    const int t = threadIdx.x;
    const int base = t * 10;
    int s = 0;
#pragma unroll
    for (int r = 0; r < 10; ++r) { int i = base + r; if (i < N_NODES) s += deg[i]; }
    part[t] = s;
    __syncthreads();
    for (int off = 1; off < 1024; off <<= 1) {
        int v = (t >= off) ? part[t - off] : 0;
        __syncthreads();
        part[t] += v;
        __syncthreads();
    }
    int run = (t > 0) ? part[t - 1] : 0;
#pragma unroll
    for (int r = 0; r < 10; ++r) {
        int i = base + r;
        if (i < N_NODES) { offs[i] = run; cursor[i] = run; run += deg[i]; }
    }
    if (t == 0) offs[N_NODES] = N_EDGES;
}

// counting-sort scatter; also computes unit vector per edge in sorted order
__global__ void k_scatter(const int* __restrict__ ei, const float* __restrict__ pos,
                          int* __restrict__ cursor, int* __restrict__ ssrc,
                          float4* __restrict__ us4) {
    int e = blockIdx.x * 256 + threadIdx.x;
    int s = ei[e], d = ei[N_EDGES + e];
    float rx = pos[d*3+0] - pos[s*3+0];
    float ry = pos[d*3+1] - pos[s*3+1];
    float rz = pos[d*3+2] - pos[s*3+2];
    float inv = 1.0f / (sqrtf(rx*rx + ry*ry + rz*rz) + 1e-9f);
    int p = atomicAdd(&cursor[d], 1);
    ssrc[p] = s;
    us4[p] = make_float4(rx*inv, ry*inv, rz*inv, 0.f);
}

// ---------- gather + W contraction + messages ----------
// Symmetric-distinct basis d in 0..9: {1, x,y,z, xx,xy,xz,yy,yz,zz}
__global__ __launch_bounds__(256) void k_gather(
    const int layer,
    const float* __restrict__ hPrev,     // [N][32][HPAD], unused for layer 0
    const float* __restrict__ emb_w,     // [32]
    const int* __restrict__ ssrc,        // [E] dst-sorted src ids
    const float4* __restrict__ us4,      // [E] dst-sorted unit vectors
    const int* __restrict__ offs,        // [N+1]
    const float* __restrict__ W_ab,      // [2][3][3][32][32]
    const float* __restrict__ ws_w,      // [2][3][3][32]
    float* __restrict__ msgd)            // [N][10][32]
{
    __shared__ __align__(16) float Tlds[SLOTS * 3 * 10 * 32];  // 30720 B
    __shared__ __align__(16) float Wlds[3 * 32 * 36];          // 13824 B

    const int slot = threadIdx.x >> 5;
    const int j    = threadIdx.x & 31;
    const int node = blockIdx.x * SLOTS + slot;

    const int e0 = offs[node], e1 = offs[node + 1];
    const int aMax = (layer == 0) ? 1 : 3;

    float T0[10], T1[10], T2[10];
#pragma unroll
    for (int d = 0; d < 10; ++d) { T0[d] = 0.f; T1[d] = 0.f; T2[d] = 0.f; }

    if (layer == 0) {
        // h0 rank-0 == emb (identical for every node): T0[d] = emb_j * sum_e up_d
        float U[10];
#pragma unroll
        for (int d = 0; d < 10; ++d) U[d] = 0.f;
        for (int idx = e0; idx < e1; ++idx) {
            const float4 u = us4[idx];
            U[0] += 1.f;
            U[1] += u.x;      U[2] += u.y;      U[3] += u.z;
            U[4] += u.x*u.x;  U[5] += u.x*u.y;  U[6] += u.x*u.z;
            U[7] += u.y*u.y;  U[8] += u.y*u.z;  U[9] += u.z*u.z;
        }
        const float s0 = emb_w[j];
#pragma unroll
        for (int d = 0; d < 10; ++d) T0[d] = s0 * U[d];
    } else {
        for (int idx = e0; idx < e1; ++idx) {
            const int src = ssrc[idx];
            const float4 u = us4[idx];
            const float* hr = hPrev + ((size_t)(src * N_CH + j)) * HPAD;
            const float4 a0 = *(const float4*)(hr);
            const float4 a1 = *(const float4*)(hr + 4);
            const float4 a2 = *(const float4*)(hr + 8);
            const float h12 = hr[12];

            const float xx = u.x*u.x, xy = u.x*u.y, xz = u.x*u.z;
            const float yy = u.y*u.y, yz = u.y*u.z, zz = u.z*u.z;
            float up[10];
            up[0] = 1.f; up[1] = u.x; up[2] = u.y; up[3] = u.z;
            up[4] = xx; up[5] = xy; up[6] = xz; up[7] = yy; up[8] = yz; up[9] = zz;

            const float s0 = a0.x;
            const float s1 = a0.y*u.x + a0.z*u.y + a0.w*u.z;
            const float s2 = a1.x*xx + (a1.y + a1.w)*xy + (a1.z + a2.z)*xz
                           + a2.x*yy + (a2.y + a2.w)*yz + h12*zz;
#pragma unroll
            for (int d = 0; d < 10; ++d) {
                T0[d] += s0 * up[d];
                T1[d] += s1 * up[d];
                T2[d] += s2 * up[d];
            }
        }
    }

    // T -> LDS, layout [slot][a][d][k=j]
#pragma unroll
    for (int d = 0; d < 10; ++d)
        Tlds[((slot * 3 + 0) * 10 + d) * 32 + j] = T0[d];
    if (layer != 0) {
#pragma unroll
        for (int d = 0; d < 10; ++d) {
            Tlds[((slot * 3 + 1) * 10 + d) * 32 + j] = T1[d];
            Tlds[((slot * 3 + 2) * 10 + d) * 32 + j] = T2[d];
        }
    }

    float acc[10];
#pragma unroll
    for (int d = 0; d < 10; ++d) acc[d] = 0.f;

#pragma unroll
    for (int c = 0; c < 3; ++c) {
        __syncthreads();   // protects Tlds stores (c==0) and Wlds reuse (c>0)
        const float* wsrc = W_ab + ((size_t)((layer * 3 + c) * 3)) * 1024;
        for (int t = threadIdx.x; t < 3072; t += 256) {
            int a = t >> 10, rem = t & 1023;
            Wlds[a * 1152 + (rem >> 5) * 36 + (rem & 31)] = wsrc[t];
        }
        __syncthreads();
        const int dlo = (c == 0) ? 0 : ((c == 1) ? 1 : 4);
        const int dhi = (c == 0) ? 1 : ((c == 1) ? 4 : 10);
        for (int a = 0; a < aMax; ++a) {
            const float* wrow = Wlds + a * 1152 + j * 36;
#pragma unroll
            for (int k4 = 0; k4 < 8; ++k4) {
                const float4 w4 = *(const float4*)(wrow + k4 * 4);
                for (int d = dlo; d < dhi; ++d) {
                    const float4 t4 = *(const float4*)&Tlds[((slot * 3 + a) * 10 + d) * 32 + k4 * 4];
                    acc[d] += dot4(w4, t4);
                }
            }
        }
    }

    // messages: msg_d = (ws0 + ws1*s0 + ws2*s0^2)_{c(d)} * acc[d]
    const float s0n = acc[0];
    const float s0sq = s0n * s0n;
    float poly[3];
#pragma unroll
    for (int c = 0; c < 3; ++c) {
        const float* wsp = ws_w + ((size_t)((layer * 3 + c) * 3)) * 32 + j;
        poly[c] = wsp[0] + wsp[32] * s0n + wsp[64] * s0sq;
    }
#pragma unroll
    for (int d = 0; d < 10; ++d) {
        const float p = (d == 0) ? poly[0] : ((d < 4) ? poly[1] : poly[2]);
        msgd[((size_t)node * 10 + d) * 32 + j] = p * acc[d];
    }
}

// ---------- node update: h_new = cw . h_old + mw . msg ----------
__global__ __launch_bounds__(256) void k_update(
    const int layer,
    const float* __restrict__ hPrev,     // [N][32][HPAD], unused for layer 0
    const float* __restrict__ emb_w,     // [32]
    const float* __restrict__ msgd,      // [N][10][32]
    const float* __restrict__ cw,        // [2][3][N][32][32]
    const float* __restrict__ mw,        // [2][3][N][32][32]
    float* __restrict__ hOut,
    const int outStride)
{
    __shared__ __align__(16) float hls[SLOTS * 13 * 32];   // 13312 B
    __shared__ __align__(16) float mls[SLOTS * 13 * 32];   // 13312 B

    const int slot = threadIdx.x >> 5;
    const int j    = threadIdx.x & 31;
    const int node = blockIdx.x * SLOTS + slot;

    // fill h_old (layer 0: rank-0 = emb, rest 0)
    if (layer == 0) {
        hls[(slot * 13 + 0) * 32 + j] = emb_w[j];
#pragma unroll
        for (int m = 1; m < 13; ++m) hls[(slot * 13 + m) * 32 + j] = 0.f;
    } else {
        const float* hr = hPrev + ((size_t)(node * N_CH + j)) * HPAD;
        const float4 a0 = *(const float4*)(hr);
        const float4 a1 = *(const float4*)(hr + 4);
        const float4 a2 = *(const float4*)(hr + 8);
        const float h12 = hr[12];
        const float hv[13] = {a0.x, a0.y, a0.z, a0.w, a1.x, a1.y, a1.z, a1.w,
                              a2.x, a2.y, a2.z, a2.w, h12};
#pragma unroll
        for (int m = 0; m < 13; ++m) hls[(slot * 13 + m) * 32 + j] = hv[m];
    }

    // fill msg with symmetric expansion d(0..9) -> m(0..12)
    {
        float md[10];
#pragma unroll
        for (int d = 0; d < 10; ++d) md[d] = msgd[((size_t)node * 10 + d) * 32 + j];
        const int mExp[13] = {0, 1, 2, 3, 4, 5, 6, 5, 7, 8, 6, 8, 9};
#pragma unroll
        for (int m = 0; m < 13; ++m) mls[(slot * 13 + m) * 32 + j] = md[mExp[m]];
    }
    __syncthreads();

    float out[13];
#pragma unroll
    for (int m = 0; m < 13; ++m) out[m] = 0.f;

#pragma unroll
    for (int c = 0; c < 3; ++c) {
        const int mlo = (c == 0) ? 0 : ((c == 1) ? 1 : 4);
        const int mhi = (c == 0) ? 1 : ((c == 1) ? 4 : 13);
        const size_t wb = (((size_t)(layer * 3 + c) * N_NODES + node) * 32 + j) * 32;
        const float4* cwr = (const float4*)(cw + wb);
        const float4* mwr = (const float4*)(mw + wb);
#pragma unroll
        for (int k4 = 0; k4 < 8; ++k4) {
            const float4 c4 = cwr[k4];
            const float4 m4 = mwr[k4];
            for (int m = mlo; m < mhi; ++m) {
                out[m] += dot4(c4, *(const float4*)&hls[(slot * 13 + m) * 32 + k4 * 4])
                        + dot4(m4, *(const float4*)&mls[(slot * 13 + m) * 32 + k4 * 4]);
            }
        }
    }

    float* orow = hOut + ((size_t)(node * N_CH + j)) * outStride;
#pragma unroll
    for (int m = 0; m < 13; ++m) orow[m] = out[m];
}

extern "C" void kernel_launch(void* const* d_in, const int* in_sizes, int n_in,
                              void* d_out, int out_size, void* d_ws, size_t ws_size,
                              hipStream_t stream) {
    const float* pos   = (const float*)d_in[0];
    const int*   ei    = (const int*)d_in[1];
    const float* emb_w = (const float*)d_in[3];
    const float* W_ab  = (const float*)d_in[4];
    const float* ws_w  = (const float*)d_in[5];
    const float* cw    = (const float*)d_in[6];
    const float* mw    = (const float*)d_in[7];
    float* out = (float*)d_out;

    char* ws = (char*)d_ws;
    float* hB   = (float*)ws; ws += (size_t)N_NODES * N_CH * HPAD * 4;   // 20.48 MB
    float4* us4 = (float4*)ws; ws += (size_t)N_EDGES * 16;               // 2.56 MB
    float* msgd = (float*)ws; ws += (size_t)N_NODES * 10 * 32 * 4;       // 12.8 MB
    int* ssrc   = (int*)ws;   ws += (size_t)N_EDGES * 4;                 // 640 KB
    int* offs   = (int*)ws;   ws += (size_t)(N_NODES + 16) * 4;
    int* cursor = (int*)ws;   ws += (size_t)N_NODES * 4;
    int* deg    = (int*)ws;   ws += (size_t)N_NODES * 4;

    hipMemsetAsync(deg, 0, N_NODES * 4, stream);
    k_hist<<<N_EDGES / 256, 256, 0, stream>>>(ei, deg);
    k_scan<<<1, 1024, 0, stream>>>(deg, offs, cursor);
    k_scatter<<<N_EDGES / 256, 256, 0, stream>>>(ei, pos, cursor, ssrc, us4);

    // layer 0 (h0 = emb broadcast; no h buffer needed)
    k_gather<<<N_NODES / SLOTS, 256, 0, stream>>>(0, (const float*)nullptr, emb_w,
                                                  ssrc, us4, offs, W_ab, ws_w, msgd);
    k_update<<<N_NODES / SLOTS, 256, 0, stream>>>(0, (const float*)nullptr, emb_w,
                                                  msgd, cw, mw, hB, HPAD);
    // layer 1
    k_gather<<<N_NODES / SLOTS, 256, 0, stream>>>(1, hB, emb_w,
                                                  ssrc, us4, offs, W_ab, ws_w, msgd);
    k_update<<<N_NODES / SLOTS, 256, 0, stream>>>(1, hB, emb_w,
                                                  msgd, cw, mw, out, 13);
}

// Round 3
// 699.669 us; speedup vs baseline: 1.3593x; 1.0348x over previous
//
#include <hip/hip_runtime.h>

#define N_NODES 10000
#define N_CH    32
#define N_EDGES 160000
#define HPAD    16      // padded h row (13 used)
#define SLOTS   8       // nodes per block

__device__ __forceinline__ float dot4(float4 a, float4 b) {
    return a.x*b.x + a.y*b.y + a.z*b.z + a.w*b.w;
}

// ---------- CSR build ----------
__global__ void k_hist(const int* __restrict__ ei, int* __restrict__ deg) {
    int e = blockIdx.x * 256 + threadIdx.x;
    atomicAdd(&deg[ei[N_EDGES + e]], 1);
}

__global__ __launch_bounds__(1024) void k_scan(const int* __restrict__ deg,
                                               int* __restrict__ offs,
                                               int* __restrict__ cursor) {
    __shared__ int part[1024];
    const int t = threadIdx.x;
    const int base = t * 10;
    int s = 0;
#pragma unroll
    for (int r = 0; r < 10; ++r) { int i = base + r; if (i < N_NODES) s += deg[i]; }
    part[t] = s;
    __syncthreads();
    for (int off = 1; off < 1024; off <<= 1) {
        int v = (t >= off) ? part[t - off] : 0;
        __syncthreads();
        part[t] += v;
        __syncthreads();
    }
    int run = (t > 0) ? part[t - 1] : 0;
#pragma unroll
    for (int r = 0; r < 10; ++r) {
        int i = base + r;
        if (i < N_NODES) { offs[i] = run; cursor[i] = run; run += deg[i]; }
    }
    if (t == 0) offs[N_NODES] = N_EDGES;
}

__global__ void k_scatter(const int* __restrict__ ei, const float* __restrict__ pos,
                          int* __restrict__ cursor, int* __restrict__ ssrc,
                          float4* __restrict__ us4) {
    int e = blockIdx.x * 256 + threadIdx.x;
    int s = ei[e], d = ei[N_EDGES + e];
    float rx = pos[d*3+0] - pos[s*3+0];
    float ry = pos[d*3+1] - pos[s*3+1];
    float rz = pos[d*3+2] - pos[s*3+2];
    float inv = 1.0f / (sqrtf(rx*rx + ry*ry + rz*rz) + 1e-9f);
    int p = atomicAdd(&cursor[d], 1);
    ssrc[p] = s;
    us4[p] = make_float4(rx*inv, ry*inv, rz*inv, 0.f);
}

// ---------- fused layer: gather -> contraction -> messages -> update ----------
// Symmetric-distinct basis d in 0..9: {1, x,y,z, xx,xy,xz,yy,yz,zz}
// m(0..12) -> d map: {0, 1,2,3, 4,5,6, 5,7,8, 6,8,9}
template<int LAYER>
__global__ __launch_bounds__(256) void k_fused(
    const float* __restrict__ hPrev,     // [N][32][HPAD] (LAYER==1 only)
    const float* __restrict__ emb_w,     // [32]
    const int* __restrict__ ssrc,        // [E] dst-sorted src ids
    const float4* __restrict__ us4,      // [E] dst-sorted unit vectors
    const int* __restrict__ offs,        // [N+1]
    const float* __restrict__ W_ab,      // [2][3][3][32][32]
    const float* __restrict__ ws_w,      // [2][3][3][32]
    const float* __restrict__ cw,        // [2][3][N][32][32]
    const float* __restrict__ mw,        // [2][3][N][32][32]
    float* __restrict__ hOut,
    const int outStride)
{
    constexpr int AMAX = (LAYER == 0) ? 1 : 3;
    // buf holds Tlds during contraction, then (hls, mls) during update.
    constexpr int TSZ   = SLOTS * AMAX * 10 * 32;                 // floats
    constexpr int MSZ   = SLOTS * 13 * 32;                        // 3328
    constexpr int HSZ   = (LAYER == 0) ? 32 : MSZ;
    constexpr int BUFSZ = (TSZ > MSZ + HSZ) ? TSZ : (MSZ + HSZ);
    __shared__ __align__(16) float buf[BUFSZ];
    __shared__ __align__(16) float Wlds[AMAX * 32 * 36];

    float* Tlds = buf;
    float* hls  = buf;              // [HSZ]
    float* mls  = buf + HSZ;        // [MSZ]

    const int slot = threadIdx.x >> 5;
    const int j    = threadIdx.x & 31;
    const int node = blockIdx.x * SLOTS + slot;

    const int e0 = offs[node], e1 = offs[node + 1];

    // ================= gather phase =================
    if (LAYER == 0) {
        // h0 rank-0 == emb (same every node): T0[d] = emb_j * sum_e up_d
        float U[10];
#pragma unroll
        for (int d = 0; d < 10; ++d) U[d] = 0.f;
        for (int idx = e0; idx < e1; ++idx) {
            const float4 u = us4[idx];
            U[0] += 1.f;
            U[1] += u.x;      U[2] += u.y;      U[3] += u.z;
            U[4] += u.x*u.x;  U[5] += u.x*u.y;  U[6] += u.x*u.z;
            U[7] += u.y*u.y;  U[8] += u.y*u.z;  U[9] += u.z*u.z;
        }
        const float s0 = emb_w[j];
#pragma unroll
        for (int d = 0; d < 10; ++d)
            Tlds[(slot * 10 + d) * 32 + j] = s0 * U[d];
    } else {
        float T0[10], T1[10], T2[10];
#pragma unroll
        for (int d = 0; d < 10; ++d) { T0[d] = 0.f; T1[d] = 0.f; T2[d] = 0.f; }
#pragma unroll 2
        for (int idx = e0; idx < e1; ++idx) {
            const int src = ssrc[idx];
            const float4 u = us4[idx];
            const float* hr = hPrev + ((size_t)(src * N_CH + j)) * HPAD;
            const float4 a0 = *(const float4*)(hr);
            const float4 a1 = *(const float4*)(hr + 4);
            const float4 a2 = *(const float4*)(hr + 8);
            const float h12 = hr[12];

            const float xx = u.x*u.x, xy = u.x*u.y, xz = u.x*u.z;
            const float yy = u.y*u.y, yz = u.y*u.z, zz = u.z*u.z;
            float up[10];
            up[0] = 1.f; up[1] = u.x; up[2] = u.y; up[3] = u.z;
            up[4] = xx; up[5] = xy; up[6] = xz; up[7] = yy; up[8] = yz; up[9] = zz;

            const float s0 = a0.x;
            const float s1 = a0.y*u.x + a0.z*u.y + a0.w*u.z;
            const float s2 = a1.x*xx + (a1.y + a1.w)*xy + (a1.z + a2.z)*xz
                           + a2.x*yy + (a2.y + a2.w)*yz + h12*zz;
#pragma unroll
            for (int d = 0; d < 10; ++d) {
                T0[d] += s0 * up[d];
                T1[d] += s1 * up[d];
                T2[d] += s2 * up[d];
            }
        }
#pragma unroll
        for (int d = 0; d < 10; ++d) {
            Tlds[((slot * 3 + 0) * 10 + d) * 32 + j] = T0[d];
            Tlds[((slot * 3 + 1) * 10 + d) * 32 + j] = T1[d];
            Tlds[((slot * 3 + 2) * 10 + d) * 32 + j] = T2[d];
        }
    }

    // ================= W contraction =================
    float acc[10];
#pragma unroll
    for (int d = 0; d < 10; ++d) acc[d] = 0.f;

#pragma unroll
    for (int c = 0; c < 3; ++c) {
        __syncthreads();   // protects Tlds stores (c==0) and Wlds reuse (c>0)
        const float* wsrc = W_ab + ((size_t)((LAYER * 3 + c) * 3)) * 1024;
        for (int t = threadIdx.x; t < AMAX * 1024; t += 256) {
            int a = t >> 10, rem = t & 1023;
            Wlds[a * 1152 + (rem >> 5) * 36 + (rem & 31)] = wsrc[t];
        }
        __syncthreads();
        const int dlo = (c == 0) ? 0 : ((c == 1) ? 1 : 4);
        const int dhi = (c == 0) ? 1 : ((c == 1) ? 4 : 10);
#pragma unroll
        for (int a = 0; a < AMAX; ++a) {
            const float* wrow = Wlds + a * 1152 + j * 36;
#pragma unroll
            for (int k4 = 0; k4 < 8; ++k4) {
                const float4 w4 = *(const float4*)(wrow + k4 * 4);
                for (int d = dlo; d < dhi; ++d) {
                    const float4 t4 = *(const float4*)&Tlds[((slot * AMAX + a) * 10 + d) * 32 + k4 * 4];
                    acc[d] += dot4(w4, t4);
                }
            }
        }
    }
    __syncthreads();  // Tlds reads done; buf re-used as hls/mls below

    // ================= messages -> LDS =================
    const float s0n = acc[0];
    const float s0sq = s0n * s0n;
    float poly[3];
#pragma unroll
    for (int c = 0; c < 3; ++c) {
        const float* wsp = ws_w + ((size_t)((LAYER * 3 + c) * 3)) * 32 + j;
        poly[c] = wsp[0] + wsp[32] * s0n + wsp[64] * s0sq;
    }
    {
        const int mExp[13] = {0, 1, 2, 3, 4, 5, 6, 5, 7, 8, 6, 8, 9};
#pragma unroll
        for (int m = 0; m < 13; ++m) {
            const float p = (m == 0) ? poly[0] : ((m < 4) ? poly[1] : poly[2]);
            mls[(slot * 13 + m) * 32 + j] = p * acc[mExp[m]];
        }
    }

    // ================= h_old -> LDS =================
    if (LAYER == 0) {
        if (threadIdx.x < 32) hls[threadIdx.x] = emb_w[threadIdx.x];
    } else {
        const float* hr = hPrev + ((size_t)(node * N_CH + j)) * HPAD;
        const float4 a0 = *(const float4*)(hr);
        const float4 a1 = *(const float4*)(hr + 4);
        const float4 a2 = *(const float4*)(hr + 8);
        const float h12 = hr[12];
        const float hv[13] = {a0.x, a0.y, a0.z, a0.w, a1.x, a1.y, a1.z, a1.w,
                              a2.x, a2.y, a2.z, a2.w, h12};
#pragma unroll
        for (int m = 0; m < 13; ++m) hls[(slot * 13 + m) * 32 + j] = hv[m];
    }
    __syncthreads();

    // ================= update =================
    float out[13];
#pragma unroll
    for (int m = 0; m < 13; ++m) out[m] = 0.f;

#pragma unroll
    for (int c = 0; c < 3; ++c) {
        const int mlo = (c == 0) ? 0 : ((c == 1) ? 1 : 4);
        const int mhi = (c == 0) ? 1 : ((c == 1) ? 4 : 13);
        const size_t wb = (((size_t)(LAYER * 3 + c) * N_NODES + node) * 32 + j) * 32;
        const float4* mwr = (const float4*)(mw + wb);
        if (LAYER == 0) {
            // h_old nonzero only at m=0 (== emb); cw[0,1],cw[0,2] multiply zeros
            if (c == 0) {
                const float4* cwr = (const float4*)(cw + wb);
#pragma unroll
                for (int k4 = 0; k4 < 8; ++k4) {
                    const float4 c4 = cwr[k4];
                    const float4 m4 = mwr[k4];
                    out[0] += dot4(c4, *(const float4*)&hls[k4 * 4])
                            + dot4(m4, *(const float4*)&mls[(slot * 13) * 32 + k4 * 4]);
                }
            } else {
#pragma unroll
                for (int k4 = 0; k4 < 8; ++k4) {
                    const float4 m4 = mwr[k4];
                    for (int m = mlo; m < mhi; ++m)
                        out[m] += dot4(m4, *(const float4*)&mls[(slot * 13 + m) * 32 + k4 * 4]);
                }
            }
        } else {
            const float4* cwr = (const float4*)(cw + wb);
#pragma unroll
            for (int k4 = 0; k4 < 8; ++k4) {
                const float4 c4 = cwr[k4];
                const float4 m4 = mwr[k4];
                for (int m = mlo; m < mhi; ++m) {
                    out[m] += dot4(c4, *(const float4*)&hls[(slot * 13 + m) * 32 + k4 * 4])
                            + dot4(m4, *(const float4*)&mls[(slot * 13 + m) * 32 + k4 * 4]);
                }
            }
        }
    }

    float* orow = hOut + ((size_t)(node * N_CH + j)) * outStride;
#pragma unroll
    for (int m = 0; m < 13; ++m) orow[m] = out[m];
}

extern "C" void kernel_launch(void* const* d_in, const int* in_sizes, int n_in,
                              void* d_out, int out_size, void* d_ws, size_t ws_size,
                              hipStream_t stream) {
    const float* pos   = (const float*)d_in[0];
    const int*   ei    = (const int*)d_in[1];
    const float* emb_w = (const float*)d_in[3];
    const float* W_ab  = (const float*)d_in[4];
    const float* ws_w  = (const float*)d_in[5];
    const float* cw    = (const float*)d_in[6];
    const float* mw    = (const float*)d_in[7];
    float* out = (float*)d_out;

    char* ws = (char*)d_ws;
    float* hB   = (float*)ws;  ws += (size_t)N_NODES * N_CH * HPAD * 4;  // 20.48 MB
    float4* us4 = (float4*)ws; ws += (size_t)N_EDGES * 16;               // 2.56 MB
    int* ssrc   = (int*)ws;    ws += (size_t)N_EDGES * 4;                // 640 KB
    int* offs   = (int*)ws;    ws += (size_t)(N_NODES + 16) * 4;
    int* cursor = (int*)ws;    ws += (size_t)N_NODES * 4;
    int* deg    = (int*)ws;    ws += (size_t)N_NODES * 4;

    hipMemsetAsync(deg, 0, N_NODES * 4, stream);
    k_hist<<<N_EDGES / 256, 256, 0, stream>>>(ei, deg);
    k_scan<<<1, 1024, 0, stream>>>(deg, offs, cursor);
    k_scatter<<<N_EDGES / 256, 256, 0, stream>>>(ei, pos, cursor, ssrc, us4);

    k_fused<0><<<N_NODES / SLOTS, 256, 0, stream>>>(nullptr, emb_w, ssrc, us4, offs,
                                                    W_ab, ws_w, cw, mw, hB, HPAD);
    k_fused<1><<<N_NODES / SLOTS, 256, 0, stream>>>(hB, emb_w, ssrc, us4, offs,
                                                    W_ab, ws_w, cw, mw, out, 13);
}